// Round 1
// 2452.176 us; speedup vs baseline: 1.2241x; 1.2241x over previous
//
#include <hip/hip_runtime.h>
#include <math.h>

// Problem constants
constexpr int NU = 100000;   // users
constexpr int NI = 50000;    // items
constexpr int NN = 150000;   // nodes
constexpr int NE = 1000000;  // edges (directed: 2*NE)
constexpr int D  = 128;

typedef __attribute__((ext_vector_type(8))) short short8v;  // 8 bf16 (4 VGPRs)
typedef __attribute__((ext_vector_type(4))) float f32x4;    // 4 fp32

__device__ __forceinline__ unsigned short f2bf(float f) {
    unsigned int u = __float_as_uint(f);
    u += 0x7FFFu + ((u >> 16) & 1u);  // round-to-nearest-even
    return (unsigned short)(u >> 16);
}
__device__ __forceinline__ float bf2f(unsigned short u) {
    return __uint_as_float(((unsigned int)u) << 16);
}

// ---------------- graph build ----------------

__global__ void k_zero(int* __restrict__ p, int n) {
    int i = blockIdx.x * 256 + threadIdx.x;
    if (i < n) p[i] = 0;
}

__global__ void k_zero16(unsigned short* __restrict__ p, int n) {
    int i = blockIdx.x * 256 + threadIdx.x;
    if (i < n) p[i] = 0;
}

__global__ void k_degree(const int* __restrict__ ei, int* __restrict__ deg) {
    int e = blockIdx.x * 256 + threadIdx.x;
    if (e < NE) {
        atomicAdd(&deg[ei[e]], 1);
        atomicAdd(&deg[ei[NE + e]], 1);
    }
}

__global__ void k_scan1(const int* __restrict__ deg, int* __restrict__ excl,
                        int* __restrict__ bsums) {
    __shared__ int s[256];
    int tid = threadIdx.x, i = blockIdx.x * 256 + tid;
    int v = (i < NN) ? deg[i] : 0;
    s[tid] = v; __syncthreads();
    for (int off = 1; off < 256; off <<= 1) {
        int t = (tid >= off) ? s[tid - off] : 0;
        __syncthreads();
        s[tid] += t;
        __syncthreads();
    }
    if (i < NN) excl[i] = s[tid] - v;
    if (tid == 255) bsums[blockIdx.x] = s[255];
}

__global__ void k_scan2(const int* __restrict__ bsums, int* __restrict__ bbase, int nb) {
    __shared__ int s[1024];
    int i = threadIdx.x;
    int v = (i < nb) ? bsums[i] : 0;
    s[i] = v; __syncthreads();
    for (int off = 1; off < 1024; off <<= 1) {
        int t = (i >= off) ? s[i - off] : 0;
        __syncthreads();
        s[i] += t;
        __syncthreads();
    }
    bbase[i] = s[i] - v;
}

__global__ void k_scan3(const int* __restrict__ deg, int* __restrict__ rowptr,
                        const int* __restrict__ bbase, int* __restrict__ cursor,
                        float* __restrict__ dis) {
    int i = blockIdx.x * 256 + threadIdx.x;
    if (i < NN) {
        int rp = rowptr[i] + bbase[blockIdx.x];
        rowptr[i] = rp;
        cursor[i] = rp;
        int d = deg[i];
        dis[i] = (d > 0) ? rsqrtf((float)d) : 0.f;
    }
    if (i == 0) rowptr[NN] = 2 * NE;
}

__global__ void k_fill(const int* __restrict__ ei, int* __restrict__ cursor,
                       int* __restrict__ colidx) {
    int e = blockIdx.x * 256 + threadIdx.x;
    if (e < NE) {
        int r = ei[e], c = ei[NE + e];
        colidx[atomicAdd(&cursor[r], 1)] = c;
        colidx[atomicAdd(&cursor[c], 1)] = r;
    }
}

// ---------------- embedding init / propagation ----------------

__global__ void k_init_emb(const float4* __restrict__ ue, const float4* __restrict__ ie,
                           float4* __restrict__ emb0, float4* __restrict__ uacc) {
    int i = blockIdx.x * 256 + threadIdx.x;  // float4 index, NN*32 total
    if (i < NN * 32) {
        float4 v = (i < NU * 32) ? ue[i] : ie[i - NU * 32];
        emb0[i] = v;
        if (i < NU * 32) uacc[i] = v;
    }
}

// one wave (64 lanes) per node; lane handles 2 dims (float2)
__global__ void k_prop(const float* __restrict__ in, float* __restrict__ out,
                       const int* __restrict__ rowptr, const int* __restrict__ colidx,
                       const float* __restrict__ dis, float* __restrict__ uacc) {
    int node = (blockIdx.x * blockDim.x + threadIdx.x) >> 6;
    int lane = threadIdx.x & 63;
    if (node >= NN) return;
    int s = rowptr[node], e = rowptr[node + 1];
    int d0 = lane * 2;
    float ax = 0.f, ay = 0.f;
    for (int j = s; j < e; ++j) {
        int c = colidx[j];
        float w = dis[c];
        float2 v = *(const float2*)(in + (size_t)c * D + d0);
        ax = fmaf(w, v.x, ax);
        ay = fmaf(w, v.y, ay);
    }
    float wn = dis[node];
    ax *= wn; ay *= wn;
    *(float2*)(out + (size_t)node * D + d0) = make_float2(ax, ay);
    if (node < NU) {
        float2* up = (float2*)(uacc + (size_t)node * D + d0);
        float2 t = *up;
        *up = make_float2(t.x + ax, t.y + ay);
    }
}

__global__ void k_scale(float4* __restrict__ p, int n4, float sc) {
    int i = blockIdx.x * 256 + threadIdx.x;
    if (i < n4) {
        float4 v = p[i];
        p[i] = make_float4(v.x * sc, v.y * sc, v.z * sc, v.w * sc);
    }
}

// ---------------- MLP heads ----------------

// Hidden layer: H_bf16[M,128] = bf16(relu(A[M,128] @ B[128,128] + bias))
// 64x64 tile, 256 threads, 4x4 per thread, K=128 fully staged in LDS (fp32 compute).
__global__ __launch_bounds__(256) void k_gemm1(
    const float* __restrict__ A, const float* __restrict__ B,
    const float* __restrict__ bias, unsigned short* __restrict__ H, int M, int N) {
    __shared__ float As[128][64];  // [k][m] (transposed A tile)
    __shared__ float Bs[128][64];  // [k][n]
    const int t = threadIdx.x;
    const int m0 = blockIdx.x * 64;
    const int n0 = blockIdx.y * 64;
    {
        int row = t & 63;
        int k0 = (t >> 6) * 4;
        const float* ap = A + (size_t)(m0 + row) * 128;
        bool okr = (m0 + row) < M;
#pragma unroll
        for (int it = 0; it < 8; ++it) {
            int kk = k0 + it * 16;
            float4 v = okr ? *(const float4*)(ap + kk) : make_float4(0, 0, 0, 0);
            As[kk + 0][row] = v.x;
            As[kk + 1][row] = v.y;
            As[kk + 2][row] = v.z;
            As[kk + 3][row] = v.w;
        }
    }
    {
        int k = t >> 4;
        int n4 = (t & 15) * 4;
        int gn = n0 + n4;
#pragma unroll
        for (int it = 0; it < 8; ++it) {
            int kk = k + it * 16;
            float4 v = *(const float4*)(B + (size_t)kk * N + gn);  // N==128 always
            *(float4*)&Bs[kk][n4] = v;
        }
    }
    __syncthreads();
    const int tm = (t >> 4) * 4;
    const int tn = (t & 15) * 4;
    float acc[4][4] = {};
#pragma unroll 4
    for (int k = 0; k < 128; ++k) {
        const float4 av = *(const float4*)&As[k][tm];
        const float4 bv = *(const float4*)&Bs[k][tn];
        const float a0 = av.x, a1 = av.y, a2 = av.z, a3 = av.w;
        const float b0 = bv.x, b1 = bv.y, b2 = bv.z, b3 = bv.w;
        acc[0][0] = fmaf(a0, b0, acc[0][0]); acc[0][1] = fmaf(a0, b1, acc[0][1]);
        acc[0][2] = fmaf(a0, b2, acc[0][2]); acc[0][3] = fmaf(a0, b3, acc[0][3]);
        acc[1][0] = fmaf(a1, b0, acc[1][0]); acc[1][1] = fmaf(a1, b1, acc[1][1]);
        acc[1][2] = fmaf(a1, b2, acc[1][2]); acc[1][3] = fmaf(a1, b3, acc[1][3]);
        acc[2][0] = fmaf(a2, b0, acc[2][0]); acc[2][1] = fmaf(a2, b1, acc[2][1]);
        acc[2][2] = fmaf(a2, b2, acc[2][2]); acc[2][3] = fmaf(a2, b3, acc[2][3]);
        acc[3][0] = fmaf(a3, b0, acc[3][0]); acc[3][1] = fmaf(a3, b1, acc[3][1]);
        acc[3][2] = fmaf(a3, b2, acc[3][2]); acc[3][3] = fmaf(a3, b3, acc[3][3]);
    }
    int colg = n0 + tn;
    {
        float4 bz = *(const float4*)(bias + colg);
#pragma unroll
        for (int i = 0; i < 4; ++i) {
            int row = m0 + tm + i;
            if (row < M) {
                float z0 = fmaxf(acc[i][0] + bz.x, 0.f);
                float z1 = fmaxf(acc[i][1] + bz.y, 0.f);
                float z2 = fmaxf(acc[i][2] + bz.z, 0.f);
                float z3 = fmaxf(acc[i][3] + bz.w, 0.f);
                ushort4 r;
                r.x = f2bf(z0); r.y = f2bf(z1); r.z = f2bf(z2); r.w = f2bf(z3);
                *(ushort4*)(H + (size_t)row * N + colg) = r;
            }
        }
    }
}

// Transpose+convert second-layer weights: BT[Npad,128] bf16 <- W[128,N] fp32
__global__ void k_bt(const float* __restrict__ w, unsigned short* __restrict__ bt,
                     int N, int Npad) {
    int i = blockIdx.x * 256 + threadIdx.x;
    if (i < Npad * 128) {
        int n = i >> 7, k = i & 127;
        bt[i] = (n < N) ? f2bf(w[(size_t)k * N + n]) : (unsigned short)0;
    }
}

// Output layer via MFMA: C[M,N] = sigmoid(A_bf16[M,128] @ BT_bf16[N,128]^T + bias)
// One wave per 64x64 tile; 4x4 fragments of v_mfma_f32_16x16x32_bf16; K=128 = 4 k-steps.
// A fragment: row = l&15, k = (l>>4)*8 + j (contiguous 16B/lane).
// B fragment: col = l&15, k = (l>>4)*8 + j -> BT[col][k...] contiguous 16B/lane.
// C/D: col = l&15, row = (l>>4)*4 + reg (m89-verified mapping).
__global__ __launch_bounds__(64) void k_gemm2_mfma(
    const unsigned short* __restrict__ A, const unsigned short* __restrict__ BT,
    const float* __restrict__ bias, float* __restrict__ C, int M, int N, int ntiles) {
    // XCD-bijective swizzle (m204): contiguous wg-chunks per XCD; n-tile fastest
    // inside a chunk so one A stripe (16KB) + whole BT stay L2-resident.
    int nwg = (int)gridDim.x;
    int orig = (int)blockIdx.x;
    int q = nwg >> 3, rr = nwg & 7;
    int xcd = orig & 7, loc = orig >> 3;
    int wg = (xcd < rr ? xcd * (q + 1) : rr * (q + 1) + (xcd - rr) * q) + loc;
    int mt = wg / ntiles;
    int nt = wg - mt * ntiles;
    const int m0 = mt * 64;
    const int n0 = nt * 64;

    const int lane = threadIdx.x;
    const int r = lane & 15;
    const int kg = lane >> 4;  // 0..3

    f32x4 acc[4][4] = {};  // [mi][ni]
#pragma unroll
    for (int kk = 0; kk < 4; ++kk) {
        short8v a[4], b[4];
#pragma unroll
        for (int mi = 0; mi < 4; ++mi)
            a[mi] = *(const short8v*)(A + (size_t)(m0 + mi * 16 + r) * 128 + kk * 32 + kg * 8);
#pragma unroll
        for (int ni = 0; ni < 4; ++ni)
            b[ni] = *(const short8v*)(BT + (size_t)(n0 + ni * 16 + r) * 128 + kk * 32 + kg * 8);
#pragma unroll
        for (int mi = 0; mi < 4; ++mi)
#pragma unroll
            for (int ni = 0; ni < 4; ++ni)
                acc[mi][ni] = __builtin_amdgcn_mfma_f32_16x16x32_bf16(
                    a[mi], b[ni], acc[mi][ni], 0, 0, 0);
    }

    const int cbase = n0 + r;
    const int rbase = m0 + (lane >> 4) * 4;
#pragma unroll
    for (int ni = 0; ni < 4; ++ni) {
        int c = cbase + ni * 16;
        if (c < N) {
            float bz = bias[c];
#pragma unroll
            for (int mi = 0; mi < 4; ++mi) {
#pragma unroll
                for (int rg = 0; rg < 4; ++rg) {
                    int row = rbase + mi * 16 + rg;
                    if (row < M) {
                        float z = acc[mi][ni][rg] + bz;
                        C[(size_t)row * N + c] = 1.f / (1.f + __expf(-z));
                    }
                }
            }
        }
    }
}

// churn head output: one wave per row, dot(h_row[128] (bf16), w2[128]) -> sigmoid
__global__ void k_churn(const unsigned short* __restrict__ h, const float* __restrict__ w2,
                        const float* __restrict__ b2, float* __restrict__ out) {
    int gw = (blockIdx.x * blockDim.x + threadIdx.x) >> 6;
    int lane = threadIdx.x & 63;
    if (gw >= NU) return;
    ushort2 hv = *(const ushort2*)(h + (size_t)gw * 128 + lane * 2);
    float2 wv = *(const float2*)(w2 + lane * 2);
    float s = bf2f(hv.x) * wv.x + bf2f(hv.y) * wv.y;
#pragma unroll
    for (int off = 32; off > 0; off >>= 1) s += __shfl_xor(s, off, 64);
    if (lane == 0) out[gw] = 1.f / (1.f + __expf(-(s + b2[0])));
}

// ---------------- launch ----------------

extern "C" void kernel_launch(void* const* d_in, const int* in_sizes, int n_in,
                              void* d_out, int out_size, void* d_ws, size_t ws_size,
                              hipStream_t stream) {
    const int*   ei  = (const int*)d_in[0];
    const float* ue  = (const float*)d_in[1];
    const float* ie  = (const float*)d_in[2];
    const float* cw1 = (const float*)d_in[3];
    const float* cb1 = (const float*)d_in[4];
    const float* cw2 = (const float*)d_in[5];
    const float* cb2 = (const float*)d_in[6];
    const float* aw1 = (const float*)d_in[7];
    const float* ab1 = (const float*)d_in[8];
    const float* aw2 = (const float*)d_in[9];
    const float* ab2 = (const float*)d_in[10];
    const float* sw1 = (const float*)d_in[11];
    const float* sb1 = (const float*)d_in[12];
    const float* sw2 = (const float*)d_in[13];
    const float* sb2 = (const float*)d_in[14];

    float* out = (float*)d_out;
    float* out_churn = out;                  // [100000,1]
    float* out_cat   = out + 100000;         // [100000,100]
    float* out_sku   = out + 10100000;       // [100000,2000]
    float* out_u     = out + 210100000;      // [100000,128]

    // workspace layout (~36 MB total)
    int*   deg    = (int*)d_ws;
    int*   rowptr = deg + 150016;     // needs 150001
    int*   cursor = rowptr + 150016;
    int*   bsums  = cursor + 150016;  // 1024
    int*   bbase  = bsums + 1024;     // 1024
    float* dis    = (float*)(bbase + 1024);      // 150016
    int*   colidx = (int*)(dis + 150016);        // 2,000,000
    unsigned short* h16 = (unsigned short*)(colidx + 2000000);  // 100096*128 bf16
    unsigned short* bt  = h16 + (size_t)100096 * 128;           // 2048*128 bf16

    // big embedding ping-pong buffers live in the (dead until last) sku region
    float* emb0 = out_sku;             // 19,200,000 floats
    float* emb1 = out_sku + 19200000;  // 19,200,000 floats

    int nb = (NN + 255) / 256;  // 586

    k_zero<<<586, 256, 0, stream>>>(deg, 150016);
    k_degree<<<(NE + 255) / 256, 256, 0, stream>>>(ei, deg);
    k_scan1<<<nb, 256, 0, stream>>>(deg, rowptr, bsums);
    k_scan2<<<1, 1024, 0, stream>>>(bsums, bbase, nb);
    k_scan3<<<nb, 256, 0, stream>>>(deg, rowptr, bbase, cursor, dis);
    k_fill<<<(NE + 255) / 256, 256, 0, stream>>>(ei, cursor, colidx);

    k_init_emb<<<(NN * 32) / 256, 256, 0, stream>>>(
        (const float4*)ue, (const float4*)ie, (float4*)emb0, (float4*)out_u);

    k_prop<<<NN / 4, 256, 0, stream>>>(emb0, emb1, rowptr, colidx, dis, out_u);
    k_prop<<<NN / 4, 256, 0, stream>>>(emb1, emb0, rowptr, colidx, dis, out_u);
    k_prop<<<NN / 4, 256, 0, stream>>>(emb0, emb1, rowptr, colidx, dis, out_u);

    k_scale<<<(NU * 32) / 256, 256, 0, stream>>>((float4*)out_u, NU * 32, 0.25f);

    // zero h16 pad rows [100000, 100096) once (A-tile edge reads must be benign)
    k_zero16<<<48, 256, 0, stream>>>(h16 + (size_t)100000 * 128, 96 * 128);

    dim3 gh((NU + 63) / 64, 2);  // hidden: N=128 -> grid.y=2
    const int mtiles = (NU + 63) / 64;  // 1563

    // churn head
    k_gemm1<<<gh, 256, 0, stream>>>(out_u, cw1, cb1, h16, NU, 128);
    k_churn<<<NU / 4, 256, 0, stream>>>(h16, cw2, cb2, out_churn);

    // cat head
    k_gemm1<<<gh, 256, 0, stream>>>(out_u, aw1, ab1, h16, NU, 128);
    k_bt<<<(128 * 128 + 255) / 256, 256, 0, stream>>>(aw2, bt, 100, 128);
    k_gemm2_mfma<<<mtiles * 2, 64, 0, stream>>>(h16, bt, ab2, out_cat, NU, 100, 2);

    // sku head (writes the whole sku region, overwriting dead emb0/emb1)
    k_gemm1<<<gh, 256, 0, stream>>>(out_u, sw1, sb1, h16, NU, 128);
    k_bt<<<(2048 * 128 + 255) / 256, 256, 0, stream>>>(sw2, bt, 2000, 2048);
    k_gemm2_mfma<<<mtiles * 32, 64, 0, stream>>>(h16, bt, sb2, out_sku, NU, 2000, 32);
}

// Round 2
// 1920.449 us; speedup vs baseline: 1.5631x; 1.2769x over previous
//
#include <hip/hip_runtime.h>
#include <math.h>

// Problem constants
constexpr int NU = 100000;   // users
constexpr int NI = 50000;    // items
constexpr int NN = 150000;   // nodes
constexpr int NE = 1000000;  // edges (directed: 2*NE)
constexpr int D  = 128;

typedef __attribute__((ext_vector_type(8))) short short8v;  // 8 bf16 (4 VGPRs)
typedef __attribute__((ext_vector_type(4))) float f32x4;    // 4 fp32

__device__ __forceinline__ unsigned short f2bf(float f) {
    unsigned int u = __float_as_uint(f);
    u += 0x7FFFu + ((u >> 16) & 1u);  // round-to-nearest-even
    return (unsigned short)(u >> 16);
}
__device__ __forceinline__ float bf2f(unsigned short u) {
    return __uint_as_float(((unsigned int)u) << 16);
}

// ---------------- graph build ----------------

__global__ void k_zero(int* __restrict__ p, int n) {
    int i = blockIdx.x * 256 + threadIdx.x;
    if (i < n) p[i] = 0;
}

__global__ void k_zero16(unsigned short* __restrict__ p, int n) {
    int i = blockIdx.x * 256 + threadIdx.x;
    if (i < n) p[i] = 0;
}

__global__ void k_degree(const int* __restrict__ ei, int* __restrict__ deg) {
    int e = blockIdx.x * 256 + threadIdx.x;
    if (e < NE) {
        atomicAdd(&deg[ei[e]], 1);
        atomicAdd(&deg[ei[NE + e]], 1);
    }
}

__global__ void k_scan1(const int* __restrict__ deg, int* __restrict__ excl,
                        int* __restrict__ bsums) {
    __shared__ int s[256];
    int tid = threadIdx.x, i = blockIdx.x * 256 + tid;
    int v = (i < NN) ? deg[i] : 0;
    s[tid] = v; __syncthreads();
    for (int off = 1; off < 256; off <<= 1) {
        int t = (tid >= off) ? s[tid - off] : 0;
        __syncthreads();
        s[tid] += t;
        __syncthreads();
    }
    if (i < NN) excl[i] = s[tid] - v;
    if (tid == 255) bsums[blockIdx.x] = s[255];
}

__global__ void k_scan2(const int* __restrict__ bsums, int* __restrict__ bbase, int nb) {
    __shared__ int s[1024];
    int i = threadIdx.x;
    int v = (i < nb) ? bsums[i] : 0;
    s[i] = v; __syncthreads();
    for (int off = 1; off < 1024; off <<= 1) {
        int t = (i >= off) ? s[i - off] : 0;
        __syncthreads();
        s[i] += t;
        __syncthreads();
    }
    bbase[i] = s[i] - v;
}

__global__ void k_scan3(const int* __restrict__ deg, int* __restrict__ rowptr,
                        const int* __restrict__ bbase, int* __restrict__ cursor,
                        float* __restrict__ dis) {
    int i = blockIdx.x * 256 + threadIdx.x;
    if (i < NN) {
        int rp = rowptr[i] + bbase[blockIdx.x];
        rowptr[i] = rp;
        cursor[i] = rp;
        int d = deg[i];
        dis[i] = (d > 0) ? rsqrtf((float)d) : 0.f;
    }
    if (i == 0) rowptr[NN] = 2 * NE;
}

__global__ void k_fill(const int* __restrict__ ei, int* __restrict__ cursor,
                       int* __restrict__ colidx) {
    int e = blockIdx.x * 256 + threadIdx.x;
    if (e < NE) {
        int r = ei[e], c = ei[NE + e];
        colidx[atomicAdd(&cursor[r], 1)] = c;
        colidx[atomicAdd(&cursor[c], 1)] = r;
    }
}

// ---------------- embedding init / propagation (bf16 ping-pong) ----------------

__global__ void k_init_emb(const float4* __restrict__ ue, const float4* __restrict__ ie,
                           ushort4* __restrict__ emb0, float4* __restrict__ uacc) {
    int i = blockIdx.x * 256 + threadIdx.x;  // float4 index, NN*32 total
    if (i < NN * 32) {
        float4 v = (i < NU * 32) ? ue[i] : ie[i - NU * 32];
        ushort4 b;
        b.x = f2bf(v.x); b.y = f2bf(v.y); b.z = f2bf(v.z); b.w = f2bf(v.w);
        emb0[i] = b;
        if (i < NU * 32) uacc[i] = v;
    }
}

// one wave (64 lanes) per node; lane handles 2 dims; bf16 in/out, fp32 accumulate
__global__ void k_prop(const unsigned short* __restrict__ in, unsigned short* __restrict__ out,
                       const int* __restrict__ rowptr, const int* __restrict__ colidx,
                       const float* __restrict__ dis, float* __restrict__ uacc) {
    int node = (blockIdx.x * blockDim.x + threadIdx.x) >> 6;
    int lane = threadIdx.x & 63;
    if (node >= NN) return;
    int s = rowptr[node], e = rowptr[node + 1];
    int d0 = lane * 2;
    float ax = 0.f, ay = 0.f;
    int j = s;
    for (; j + 4 <= e; j += 4) {
        int c0 = colidx[j], c1 = colidx[j + 1], c2 = colidx[j + 2], c3 = colidx[j + 3];
        float w0 = dis[c0], w1 = dis[c1], w2 = dis[c2], w3 = dis[c3];
        ushort2 v0 = *(const ushort2*)(in + (size_t)c0 * D + d0);
        ushort2 v1 = *(const ushort2*)(in + (size_t)c1 * D + d0);
        ushort2 v2 = *(const ushort2*)(in + (size_t)c2 * D + d0);
        ushort2 v3 = *(const ushort2*)(in + (size_t)c3 * D + d0);
        ax = fmaf(w0, bf2f(v0.x), ax); ay = fmaf(w0, bf2f(v0.y), ay);
        ax = fmaf(w1, bf2f(v1.x), ax); ay = fmaf(w1, bf2f(v1.y), ay);
        ax = fmaf(w2, bf2f(v2.x), ax); ay = fmaf(w2, bf2f(v2.y), ay);
        ax = fmaf(w3, bf2f(v3.x), ax); ay = fmaf(w3, bf2f(v3.y), ay);
    }
    for (; j < e; ++j) {
        int c = colidx[j];
        float w = dis[c];
        ushort2 v = *(const ushort2*)(in + (size_t)c * D + d0);
        ax = fmaf(w, bf2f(v.x), ax);
        ay = fmaf(w, bf2f(v.y), ay);
    }
    float wn = dis[node];
    ax *= wn; ay *= wn;
    ushort2 o; o.x = f2bf(ax); o.y = f2bf(ay);
    *(ushort2*)(out + (size_t)node * D + d0) = o;
    if (node < NU) {
        float2* up = (float2*)(uacc + (size_t)node * D + d0);
        float2 t = *up;
        *up = make_float2(t.x + ax, t.y + ay);
    }
}

__global__ void k_scale(float4* __restrict__ p, int n4, float sc) {
    int i = blockIdx.x * 256 + threadIdx.x;
    if (i < n4) {
        float4 v = p[i];
        p[i] = make_float4(v.x * sc, v.y * sc, v.z * sc, v.w * sc);
    }
}

// ---------------- MLP heads ----------------

// Hidden layer: H_bf16[M,128] = bf16(relu(A[M,128] @ B[128,128] + bias))
// 64x64 tile, 256 threads, 4x4 per thread, K=128 fully staged in LDS (fp32 compute).
__global__ __launch_bounds__(256) void k_gemm1(
    const float* __restrict__ A, const float* __restrict__ B,
    const float* __restrict__ bias, unsigned short* __restrict__ H, int M, int N) {
    __shared__ float As[128][64];  // [k][m] (transposed A tile)
    __shared__ float Bs[128][64];  // [k][n]
    const int t = threadIdx.x;
    const int m0 = blockIdx.x * 64;
    const int n0 = blockIdx.y * 64;
    {
        int row = t & 63;
        int k0 = (t >> 6) * 4;
        const float* ap = A + (size_t)(m0 + row) * 128;
        bool okr = (m0 + row) < M;
#pragma unroll
        for (int it = 0; it < 8; ++it) {
            int kk = k0 + it * 16;
            float4 v = okr ? *(const float4*)(ap + kk) : make_float4(0, 0, 0, 0);
            As[kk + 0][row] = v.x;
            As[kk + 1][row] = v.y;
            As[kk + 2][row] = v.z;
            As[kk + 3][row] = v.w;
        }
    }
    {
        int k = t >> 4;
        int n4 = (t & 15) * 4;
        int gn = n0 + n4;
#pragma unroll
        for (int it = 0; it < 8; ++it) {
            int kk = k + it * 16;
            float4 v = *(const float4*)(B + (size_t)kk * N + gn);  // N==128 always
            *(float4*)&Bs[kk][n4] = v;
        }
    }
    __syncthreads();
    const int tm = (t >> 4) * 4;
    const int tn = (t & 15) * 4;
    float acc[4][4] = {};
#pragma unroll 4
    for (int k = 0; k < 128; ++k) {
        const float4 av = *(const float4*)&As[k][tm];
        const float4 bv = *(const float4*)&Bs[k][tn];
        const float a0 = av.x, a1 = av.y, a2 = av.z, a3 = av.w;
        const float b0 = bv.x, b1 = bv.y, b2 = bv.z, b3 = bv.w;
        acc[0][0] = fmaf(a0, b0, acc[0][0]); acc[0][1] = fmaf(a0, b1, acc[0][1]);
        acc[0][2] = fmaf(a0, b2, acc[0][2]); acc[0][3] = fmaf(a0, b3, acc[0][3]);
        acc[1][0] = fmaf(a1, b0, acc[1][0]); acc[1][1] = fmaf(a1, b1, acc[1][1]);
        acc[1][2] = fmaf(a1, b2, acc[1][2]); acc[1][3] = fmaf(a1, b3, acc[1][3]);
        acc[2][0] = fmaf(a2, b0, acc[2][0]); acc[2][1] = fmaf(a2, b1, acc[2][1]);
        acc[2][2] = fmaf(a2, b2, acc[2][2]); acc[2][3] = fmaf(a2, b3, acc[2][3]);
        acc[3][0] = fmaf(a3, b0, acc[3][0]); acc[3][1] = fmaf(a3, b1, acc[3][1]);
        acc[3][2] = fmaf(a3, b2, acc[3][2]); acc[3][3] = fmaf(a3, b3, acc[3][3]);
    }
    int colg = n0 + tn;
    {
        float4 bz = *(const float4*)(bias + colg);
#pragma unroll
        for (int i = 0; i < 4; ++i) {
            int row = m0 + tm + i;
            if (row < M) {
                float z0 = fmaxf(acc[i][0] + bz.x, 0.f);
                float z1 = fmaxf(acc[i][1] + bz.y, 0.f);
                float z2 = fmaxf(acc[i][2] + bz.z, 0.f);
                float z3 = fmaxf(acc[i][3] + bz.w, 0.f);
                ushort4 r;
                r.x = f2bf(z0); r.y = f2bf(z1); r.z = f2bf(z2); r.w = f2bf(z3);
                *(ushort4*)(H + (size_t)row * N + colg) = r;
            }
        }
    }
}

// Transpose+convert second-layer weights: BT[Npad,128] bf16 <- W[128,N] fp32
__global__ void k_bt(const float* __restrict__ w, unsigned short* __restrict__ bt,
                     int N, int Npad) {
    int i = blockIdx.x * 256 + threadIdx.x;
    if (i < Npad * 128) {
        int n = i >> 7, k = i & 127;
        bt[i] = (n < N) ? f2bf(w[(size_t)k * N + n]) : (unsigned short)0;
    }
}

// Output layer via MFMA: C[M,N] = sigmoid(A_bf16[M,128] @ BT_bf16[N,128]^T + bias)
// 128x128 tile per block, 4 waves (2x2 of 64x64), K=128 = 4 k-steps of 16x16x32.
// Epilogue stages through LDS for fully-coalesced float4 stores.
// A fragment: row = l&15, k = (l>>4)*8 + j. B fragment: col = l&15, same k.
// C/D: col = l&15, row = (l>>4)*4 + reg (m89-verified mapping).
__global__ __launch_bounds__(256) void k_gemm2(
    const unsigned short* __restrict__ A, const unsigned short* __restrict__ BT,
    const float* __restrict__ bias, float* __restrict__ C, int M, int N, int ntiles) {
    __shared__ float tile[128][132];
    // XCD-bijective swizzle (m204): contiguous wg-chunks per XCD.
    int nwg = (int)gridDim.x;
    int orig = (int)blockIdx.x;
    int q = nwg >> 3, rr = nwg & 7;
    int xcd = orig & 7, loc = orig >> 3;
    int wg = (xcd < rr ? xcd * (q + 1) : rr * (q + 1) + (xcd - rr) * q) + loc;
    int mt = wg / ntiles;
    int nt = wg - mt * ntiles;
    const int m0 = mt * 128;
    const int n0 = nt * 128;

    const int t = threadIdx.x;
    const int wid = t >> 6;
    const int lane = t & 63;
    const int wm = (wid & 1) * 64;   // wave's 64-row quadrant
    const int wn = (wid >> 1) * 64;  // wave's 64-col quadrant
    const int r = lane & 15;
    const int kg = lane >> 4;  // 0..3

    const unsigned short* Ap = A + (size_t)(m0 + wm + r) * 128 + kg * 8;
    const unsigned short* Bp = BT + (size_t)(n0 + wn + r) * 128 + kg * 8;

    f32x4 acc[4][4] = {};  // [mi][ni]
#pragma unroll
    for (int kk = 0; kk < 4; ++kk) {
        short8v a[4], b[4];
#pragma unroll
        for (int mi = 0; mi < 4; ++mi)
            a[mi] = *(const short8v*)(Ap + (size_t)mi * 16 * 128 + kk * 32);
#pragma unroll
        for (int ni = 0; ni < 4; ++ni)
            b[ni] = *(const short8v*)(Bp + (size_t)ni * 16 * 128 + kk * 32);
#pragma unroll
        for (int mi = 0; mi < 4; ++mi)
#pragma unroll
            for (int ni = 0; ni < 4; ++ni)
                acc[mi][ni] = __builtin_amdgcn_mfma_f32_16x16x32_bf16(
                    a[mi], b[ni], acc[mi][ni], 0, 0, 0);
    }

    // stage accumulators to LDS: row = wm + mi*16 + kg*4 + rg, col = wn + ni*16 + r
#pragma unroll
    for (int mi = 0; mi < 4; ++mi)
#pragma unroll
        for (int ni = 0; ni < 4; ++ni)
#pragma unroll
            for (int rg = 0; rg < 4; ++rg)
                tile[wm + mi * 16 + kg * 4 + rg][wn + ni * 16 + r] = acc[mi][ni][rg];
    __syncthreads();

    // coalesced write-out: 8 rows x 32 lanes x float4 per sweep, 16 sweeps
    const int rsub = t >> 5;        // 0..7
    const int c4 = (t & 31) * 4;    // 0..124
    const int colg = n0 + c4;
    const bool okc = colg < N;      // N%4==0 in all uses
    float4 bz = okc ? *(const float4*)(bias + colg) : make_float4(0, 0, 0, 0);
#pragma unroll
    for (int rb = 0; rb < 16; ++rb) {
        int row = rb * 8 + rsub;
        int rowg = m0 + row;
        if (okc && rowg < M) {
            float4 v = *(const float4*)&tile[row][c4];
            float4 o;
            o.x = 1.f / (1.f + __expf(-(v.x + bz.x)));
            o.y = 1.f / (1.f + __expf(-(v.y + bz.y)));
            o.z = 1.f / (1.f + __expf(-(v.z + bz.z)));
            o.w = 1.f / (1.f + __expf(-(v.w + bz.w)));
            *(float4*)(C + (size_t)rowg * N + colg) = o;
        }
    }
}

// churn head output: one wave per row, dot(h_row[128] (bf16), w2[128]) -> sigmoid
__global__ void k_churn(const unsigned short* __restrict__ h, const float* __restrict__ w2,
                        const float* __restrict__ b2, float* __restrict__ out) {
    int gw = (blockIdx.x * blockDim.x + threadIdx.x) >> 6;
    int lane = threadIdx.x & 63;
    if (gw >= NU) return;
    ushort2 hv = *(const ushort2*)(h + (size_t)gw * 128 + lane * 2);
    float2 wv = *(const float2*)(w2 + lane * 2);
    float s = bf2f(hv.x) * wv.x + bf2f(hv.y) * wv.y;
#pragma unroll
    for (int off = 32; off > 0; off >>= 1) s += __shfl_xor(s, off, 64);
    if (lane == 0) out[gw] = 1.f / (1.f + __expf(-(s + b2[0])));
}

// ---------------- launch ----------------

extern "C" void kernel_launch(void* const* d_in, const int* in_sizes, int n_in,
                              void* d_out, int out_size, void* d_ws, size_t ws_size,
                              hipStream_t stream) {
    const int*   ei  = (const int*)d_in[0];
    const float* ue  = (const float*)d_in[1];
    const float* ie  = (const float*)d_in[2];
    const float* cw1 = (const float*)d_in[3];
    const float* cb1 = (const float*)d_in[4];
    const float* cw2 = (const float*)d_in[5];
    const float* cb2 = (const float*)d_in[6];
    const float* aw1 = (const float*)d_in[7];
    const float* ab1 = (const float*)d_in[8];
    const float* aw2 = (const float*)d_in[9];
    const float* ab2 = (const float*)d_in[10];
    const float* sw1 = (const float*)d_in[11];
    const float* sb1 = (const float*)d_in[12];
    const float* sw2 = (const float*)d_in[13];
    const float* sb2 = (const float*)d_in[14];

    float* out = (float*)d_out;
    float* out_churn = out;                  // [100000,1]
    float* out_cat   = out + 100000;         // [100000,100]
    float* out_sku   = out + 10100000;       // [100000,2000]
    float* out_u     = out + 210100000;      // [100000,128]

    // workspace layout (~36 MB total)
    int*   deg    = (int*)d_ws;
    int*   rowptr = deg + 150016;     // needs 150001
    int*   cursor = rowptr + 150016;
    int*   bsums  = cursor + 150016;  // 1024
    int*   bbase  = bsums + 1024;     // 1024
    float* dis    = (float*)(bbase + 1024);      // 150016
    int*   colidx = (int*)(dis + 150016);        // 2,000,000
    unsigned short* h16 = (unsigned short*)(colidx + 2000000);  // 100096*128 bf16
    unsigned short* bt  = h16 + (size_t)100096 * 128;           // 2048*128 bf16

    // bf16 embedding ping-pong buffers live in the (dead until last) sku region
    unsigned short* emb0 = (unsigned short*)out_sku;   // NN*128 bf16 = 38.4 MB
    unsigned short* emb1 = emb0 + (size_t)NN * 128;    // 38.4 MB

    int nb = (NN + 255) / 256;  // 586

    k_zero<<<586, 256, 0, stream>>>(deg, 150016);
    k_degree<<<(NE + 255) / 256, 256, 0, stream>>>(ei, deg);
    k_scan1<<<nb, 256, 0, stream>>>(deg, rowptr, bsums);
    k_scan2<<<1, 1024, 0, stream>>>(bsums, bbase, nb);
    k_scan3<<<nb, 256, 0, stream>>>(deg, rowptr, bbase, cursor, dis);
    k_fill<<<(NE + 255) / 256, 256, 0, stream>>>(ei, cursor, colidx);

    k_init_emb<<<(NN * 32) / 256, 256, 0, stream>>>(
        (const float4*)ue, (const float4*)ie, (ushort4*)emb0, (float4*)out_u);

    k_prop<<<NN / 4, 256, 0, stream>>>(emb0, emb1, rowptr, colidx, dis, out_u);
    k_prop<<<NN / 4, 256, 0, stream>>>(emb1, emb0, rowptr, colidx, dis, out_u);
    k_prop<<<NN / 4, 256, 0, stream>>>(emb0, emb1, rowptr, colidx, dis, out_u);

    k_scale<<<(NU * 32) / 256, 256, 0, stream>>>((float4*)out_u, NU * 32, 0.25f);

    // zero h16 pad rows [100000, 100096) once (A-tile edge reads must be benign)
    k_zero16<<<48, 256, 0, stream>>>(h16 + (size_t)100000 * 128, 96 * 128);

    dim3 gh((NU + 63) / 64, 2);  // hidden: N=128 -> grid.y=2
    const int mtiles128 = 100096 / 128;  // 782 (h16 padded to exactly 782*128 rows)

    // churn head
    k_gemm1<<<gh, 256, 0, stream>>>(out_u, cw1, cb1, h16, NU, 128);
    k_churn<<<NU / 4, 256, 0, stream>>>(h16, cw2, cb2, out_churn);

    // cat head
    k_gemm1<<<gh, 256, 0, stream>>>(out_u, aw1, ab1, h16, NU, 128);
    k_bt<<<(128 * 128 + 255) / 256, 256, 0, stream>>>(aw2, bt, 100, 128);
    k_gemm2<<<mtiles128 * 1, 256, 0, stream>>>(h16, bt, ab2, out_cat, NU, 100, 1);

    // sku head (writes the whole sku region, overwriting dead emb0/emb1)
    k_gemm1<<<gh, 256, 0, stream>>>(out_u, sw1, sb1, h16, NU, 128);
    k_bt<<<(2048 * 128 + 255) / 256, 256, 0, stream>>>(sw2, bt, 2000, 2048);
    k_gemm2<<<mtiles128 * 16, 256, 0, stream>>>(h16, bt, sb2, out_sku, NU, 2000, 16);
}